// Round 7
// baseline (541.629 us; speedup 1.0000x reference)
//
#include <hip/hip_runtime.h>
#include <cstdint>
#include <cmath>

#define NN 4096
#define FF 512
#define HH 64
#define KSPLIT 8

typedef unsigned short ushort_t;
typedef short bf16x8 __attribute__((ext_vector_type(8)));
typedef float f32x4 __attribute__((ext_vector_type(4)));

// ---------------- threefry2x32 (JAX-compatible, 20 rounds) ----------------
__host__ __device__ __forceinline__ uint32_t rotl32(uint32_t x, int r) {
    return (x << r) | (x >> (32 - r));
}

__host__ __device__ __forceinline__ void threefry2x32(uint32_t ks0, uint32_t ks1,
                                                      uint32_t x0, uint32_t x1,
                                                      uint32_t& o0, uint32_t& o1) {
    uint32_t ks2 = ks0 ^ ks1 ^ 0x1BD11BDAu;
    x0 += ks0; x1 += ks1;
    x0 += x1; x1 = rotl32(x1, 13); x1 ^= x0;
    x0 += x1; x1 = rotl32(x1, 15); x1 ^= x0;
    x0 += x1; x1 = rotl32(x1, 26); x1 ^= x0;
    x0 += x1; x1 = rotl32(x1,  6); x1 ^= x0;
    x0 += ks1; x1 += ks2 + 1u;
    x0 += x1; x1 = rotl32(x1, 17); x1 ^= x0;
    x0 += x1; x1 = rotl32(x1, 29); x1 ^= x0;
    x0 += x1; x1 = rotl32(x1, 16); x1 ^= x0;
    x0 += x1; x1 = rotl32(x1, 24); x1 ^= x0;
    x0 += ks2; x1 += ks0 + 2u;
    x0 += x1; x1 = rotl32(x1, 13); x1 ^= x0;
    x0 += x1; x1 = rotl32(x1, 15); x1 ^= x0;
    x0 += x1; x1 = rotl32(x1, 26); x1 ^= x0;
    x0 += x1; x1 = rotl32(x1,  6); x1 ^= x0;
    x0 += ks0; x1 += ks1 + 3u;
    x0 += x1; x1 = rotl32(x1, 17); x1 ^= x0;
    x0 += x1; x1 = rotl32(x1, 29); x1 ^= x0;
    x0 += x1; x1 = rotl32(x1, 16); x1 ^= x0;
    x0 += x1; x1 = rotl32(x1, 24); x1 ^= x0;
    x0 += ks1; x1 += ks2 + 4u;
    x0 += x1; x1 = rotl32(x1, 13); x1 ^= x0;
    x0 += x1; x1 = rotl32(x1, 15); x1 ^= x0;
    x0 += x1; x1 = rotl32(x1, 26); x1 ^= x0;
    x0 += x1; x1 = rotl32(x1,  6); x1 ^= x0;
    x0 += ks2; x1 += ks0 + 5u;
    o0 = x0; o1 = x1;
}

__device__ __forceinline__ uint32_t jax_bits32(uint32_t k0, uint32_t k1, uint32_t j) {
    uint32_t b0, b1;
    threefry2x32(k0, k1, 0u, j, b0, b1);
    return b0 ^ b1;
}

__device__ __forceinline__ float jax_uniform(uint32_t bits) {
    const float minv = 1e-6f;
    const float maxv = (float)(1.0 - 1e-6);
    const float span = maxv - minv;
    float f = __uint_as_float((bits >> 9) | 0x3f800000u) - 1.0f;
    float u = __fadd_rn(__fmul_rn(f, span), minv);
    return fmaxf(minv, u);
}

// hard Bernoulli-ST forward: 1[ l + logit(u) > 0 ]  <=>  u > 1/(1+e^l)
__device__ __forceinline__ float hard_sample_f(float l, float u) {
    float thr = 1.0f / (1.0f + expf(l));
    return (u > thr) ? 1.0f : 0.0f;
}

__device__ __forceinline__ ushort_t f32_to_bf16_rne(float f) {
    uint32_t x = __float_as_uint(f);
    uint32_t r = (x + 0x7fffu + ((x >> 16) & 1u)) >> 16;
    return (ushort_t)r;
}

// ---------------- pipeline kernels ----------------

// Tt[64,4096] (bf16, transposed) = (x[4096,512] @ Wg[512,64])^T
__global__ void k_xw(const float* __restrict__ x, const float* __restrict__ Wg,
                     ushort_t* __restrict__ Tt) {
    __shared__ ushort_t Tls[4][64];
    int col = threadIdx.x, ty = threadIdx.y;
    int row = blockIdx.x * 4 + ty;
    const float* xr = x + row * FF;
    float acc = 0.0f;
    #pragma unroll 4
    for (int k = 0; k < FF; ++k)
        acc += xr[k] * Wg[k * HH + col];
    Tls[ty][col] = f32_to_bf16_rne(acc);
    __syncthreads();
    int t = ty * 64 + col;
    if (t < 64) {
        uint2 v;
        ushort_t* p = (ushort_t*)&v;
        p[0] = Tls[0][t]; p[1] = Tls[1][t]; p[2] = Tls[2][t]; p[3] = Tls[3][t];
        *(uint2*)&Tt[(size_t)t * NN + blockIdx.x * 4] = v;
    }
}

// partial[s][4096][64] += adj(bf16-cvt)[*,Kslice] @ T[Kslice,*] via MFMA.
__global__ void __launch_bounds__(256)
k_adjT_mfma(const float* __restrict__ adj, const ushort_t* __restrict__ Tt,
            float* __restrict__ partial) {
    __shared__ __align__(16) ushort_t As[64][72];
    __shared__ __align__(16) ushort_t Tl[64][72];
    int t = threadIdx.x;
    int lane = t & 63, w = t >> 6;
    int lr = lane & 15, lk = lane >> 4;
    int r0 = blockIdx.x * 64;
    int kb = blockIdx.y * (NN / KSPLIT);
    f32x4 acc[4] = {};
    for (int k0 = 0; k0 < NN / KSPLIT; k0 += 64) {
        __syncthreads();
        #pragma unroll
        for (int i = 0; i < 4; ++i) {
            int idx = t + i * 256;
            int rr = idx >> 4;
            int kq = (idx & 15) * 4;
            float4 v = *(const float4*)&adj[(size_t)(r0 + rr) * NN + kb + k0 + kq];
            uint32_t lo = (uint32_t)f32_to_bf16_rne(v.x) | ((uint32_t)f32_to_bf16_rne(v.y) << 16);
            uint32_t hi = (uint32_t)f32_to_bf16_rne(v.z) | ((uint32_t)f32_to_bf16_rne(v.w) << 16);
            uint2 pk = {lo, hi};
            *(uint2*)&As[rr][kq] = pk;
        }
        #pragma unroll
        for (int i = 0; i < 2; ++i) {
            int idx = t + i * 256;
            int cc = idx >> 3;
            int kq = (idx & 7) * 8;
            *(uint4*)&Tl[cc][kq] = *(const uint4*)&Tt[(size_t)cc * NN + kb + k0 + kq];
        }
        __syncthreads();
        #pragma unroll
        for (int ks = 0; ks < 2; ++ks) {
            bf16x8 a = *(const bf16x8*)&As[w * 16 + lr][ks * 32 + lk * 8];
            #pragma unroll
            for (int c = 0; c < 4; ++c) {
                bf16x8 bb = *(const bf16x8*)&Tl[c * 16 + lr][ks * 32 + lk * 8];
                acc[c] = __builtin_amdgcn_mfma_f32_16x16x32_bf16(a, bb, acc[c], 0, 0, 0);
            }
        }
    }
    float* P = partial + (size_t)blockIdx.y * NN * HH;
    #pragma unroll
    for (int c = 0; c < 4; ++c)
        #pragma unroll
        for (int reg = 0; reg < 4; ++reg)
            P[(size_t)(r0 + w * 16 + lk * 4 + reg) * HH + c * 16 + lr] = acc[c][reg];
}

// Merged MLP kernel: inline hred (partial-sum + bias + relu) for 8 rows, then
// BOTH heads: Zb = (relu(h@Wa1+ba1))@Wa2+ba2 (bf16 store) and
// xnew = x * mask(relu(h@Wx1+bx1)@Wx2+bx2).  Replaces k_hred+k_mlpZ+k_mlpM
// (saves 2 launches + the 3 MB h round-trip). Must run BEFORE k_zzt_fused:
// it reads `partial`, which zzt overwrites via the aliased `mask` buffer.
__global__ void __launch_bounds__(256)
k_mlp(const float* __restrict__ partial, const float* __restrict__ bg,
      const float* __restrict__ Wa1, const float* __restrict__ ba1,
      const float* __restrict__ Wa2, const float* __restrict__ ba2,
      const float* __restrict__ Wx1, const float* __restrict__ bx1,
      const float* __restrict__ Wx2, const float* __restrict__ bx2,
      const float* __restrict__ x, ushort_t* __restrict__ Zb,
      float* __restrict__ xnew, uint32_t k20, uint32_t k21,
      float Lmin, float Lmax) {
    __shared__ float W1l[HH][HH];
    __shared__ float A1l[8][HH];
    __shared__ float hl[8][HH];
    int t = threadIdx.x;
    int r0 = blockIdx.x * 8;
    // inline hred: hl = relu(sum_p partial[p][r0..r0+8][:] + bg)
    for (int n = t; n < 8 * HH; n += 256) {
        float s = 0.0f;
        #pragma unroll
        for (int p = 0; p < KSPLIT; ++p)
            s += partial[(size_t)p * NN * HH + (size_t)r0 * HH + n];
        float v = s + bg[n & (HH - 1)];
        ((float*)hl)[n] = v > 0.0f ? v : 0.0f;
    }
    for (int n = t; n < HH * HH; n += 256) ((float*)W1l)[n] = Wa1[n];
    __syncthreads();
    // ---- head A: Zb ----
    {
        int col = t & 63;
        int rb = t >> 6;
        #pragma unroll
        for (int rr = 0; rr < 2; ++rr) {
            int row = rb * 2 + rr;
            float acc = ba1[col];
            #pragma unroll
            for (int k = 0; k < HH; ++k) acc += hl[row][k] * W1l[k][col];
            A1l[row][col] = acc > 0.0f ? acc : 0.0f;
        }
    }
    __syncthreads();
    #pragma unroll
    for (int p = 0; p < 2; ++p) {
        int col = p * 256 + t;
        float wc[HH];
        #pragma unroll
        for (int k = 0; k < HH; ++k) wc[k] = Wa2[k * FF + col];
        float bb = ba2[col];
        #pragma unroll
        for (int row = 0; row < 8; ++row) {
            float acc = bb;
            #pragma unroll
            for (int k = 0; k < HH; ++k) acc += A1l[row][k] * wc[k];
            Zb[(size_t)(r0 + row) * FF + col] = f32_to_bf16_rne(acc);
        }
    }
    __syncthreads();   // all A1l reads done before overwrite
    // ---- head X: feature mask ----
    for (int n = t; n < HH * HH; n += 256) ((float*)W1l)[n] = Wx1[n];
    __syncthreads();
    {
        int col = t & 63;
        int rb = t >> 6;
        #pragma unroll
        for (int rr = 0; rr < 2; ++rr) {
            int row = rb * 2 + rr;
            float acc = bx1[col];
            #pragma unroll
            for (int k = 0; k < HH; ++k) acc += hl[row][k] * W1l[k][col];
            A1l[row][col] = acc > 0.0f ? acc : 0.0f;
        }
    }
    __syncthreads();
    #pragma unroll
    for (int p = 0; p < 2; ++p) {
        int col = p * 256 + t;
        float wc[HH];
        #pragma unroll
        for (int k = 0; k < HH; ++k) wc[k] = Wx2[k * FF + col];
        float bb = bx2[col];
        #pragma unroll
        for (int row = 0; row < 8; ++row) {
            float acc = bb;
            #pragma unroll
            for (int k = 0; k < HH; ++k) acc += A1l[row][k] * wc[k];
            float ml = acc;
            float l = ml < Lmin ? Lmin : (ml > Lmax ? Lmax : ml);
            uint32_t idx = (uint32_t)(r0 + row) * FF + (uint32_t)col;
            float u = jax_uniform(jax_bits32(k20, k21, idx));
            float m = hard_sample_f(l, u);
            size_t gi = (size_t)(r0 + row) * FF + col;
            xnew[gi] = (m != 0.0f) ? x[gi] : 0.0f;
        }
    }
}

// adj_logits = Zb @ Zb^T (bf16 MFMA, triangular 528 blocks) + FUSED sampling.
// Round-7: T14 async-stage split — next K-tile prefetched into VGPRs
// (8x uint4) and written to LDS at the top of the next iter, so global-load
// latency hides under MFMA+barrier instead of sitting between barriers.
// All acc indices compile-time constant (rule #20; round-5 spill lesson).
__global__ void __launch_bounds__(256)
k_zzt_fused(const ushort_t* __restrict__ Zb, float* __restrict__ out2,
            uint32_t* __restrict__ mask, float* __restrict__ rowsum,
            uint32_t k10, uint32_t k11, float Lmin, float Lmax) {
    __shared__ __align__(16) union {
        struct { ushort_t At[128][72]; ushort_t Bt[128][72]; } s;  // 36.9 KB
        float Tls[32][132];                                         // 16.9 KB
    } sm;
    __shared__ uint32_t Wl[128][5];
    __shared__ int rs_i[128], cs_i[128];
    int t = threadIdx.x;
    int lane = t & 63, w = t >> 6;
    int lr = lane & 15, lk = lane >> 4;
    if (t < 128) { rs_i[t] = 0; cs_i[t] = 0; }
    int b = blockIdx.x, bi = 0;
    while (b >= 32 - bi) { b -= 32 - bi; ++bi; }
    int bj = bi + b;
    int rbase = bi * 128, cbase = bj * 128;
    f32x4 acc[2][8] = {};
    uint4 pa[4], pb[4];
    #pragma unroll
    for (int i = 0; i < 4; ++i) {
        int n = t + i * 256;
        int rr = n >> 3, ck = n & 7;
        pa[i] = *(const uint4*)&Zb[(size_t)(rbase + rr) * FF + ck * 8];
        pb[i] = *(const uint4*)&Zb[(size_t)(cbase + rr) * FF + ck * 8];
    }
    for (int k0 = 0; k0 < FF; k0 += 64) {
        __syncthreads();           // prev MFMA done reading LDS
        #pragma unroll
        for (int i = 0; i < 4; ++i) {
            int n = t + i * 256;
            int rr = n >> 3, ck = n & 7;
            *(uint4*)&sm.s.At[rr][ck * 8] = pa[i];
            *(uint4*)&sm.s.Bt[rr][ck * 8] = pb[i];
        }
        if (k0 + 64 < FF) {        // issue next-tile loads; latency hides under MFMA
            #pragma unroll
            for (int i = 0; i < 4; ++i) {
                int n = t + i * 256;
                int rr = n >> 3, ck = n & 7;
                pa[i] = *(const uint4*)&Zb[(size_t)(rbase + rr) * FF + k0 + 64 + ck * 8];
                pb[i] = *(const uint4*)&Zb[(size_t)(cbase + rr) * FF + k0 + 64 + ck * 8];
            }
        }
        __syncthreads();
        #pragma unroll
        for (int ks = 0; ks < 2; ++ks) {
            bf16x8 a0 = *(const bf16x8*)&sm.s.At[w * 32 + lr][ks * 32 + lk * 8];
            bf16x8 a1 = *(const bf16x8*)&sm.s.At[w * 32 + 16 + lr][ks * 32 + lk * 8];
            #pragma unroll
            for (int j = 0; j < 8; ++j) {
                bf16x8 bb = *(const bf16x8*)&sm.s.Bt[j * 16 + lr][ks * 32 + lk * 8];
                acc[0][j] = __builtin_amdgcn_mfma_f32_16x16x32_bf16(a0, bb, acc[0][j], 0, 0, 0);
                acc[1][j] = __builtin_amdgcn_mfma_f32_16x16x32_bf16(a1, bb, acc[1][j], 0, 0, 0);
            }
        }
    }
    // direct (bi,bj) tile store — row-major coalesced
    #pragma unroll
    for (int it = 0; it < 2; ++it) {
        int rg = rbase + w * 32 + it * 16 + lk * 4;
        #pragma unroll
        for (int reg = 0; reg < 4; ++reg)
            #pragma unroll
            for (int j = 0; j < 8; ++j)
                out2[(size_t)(rg + reg) * NN + cbase + j * 16 + lr] = acc[it][j][reg];
    }
    // 4 col-chunks: mirror-transpose store (off-diag) + fused sampling (all).
    #pragma unroll
    for (int g = 0; g < 4; ++g) {
        __syncthreads();
        #pragma unroll
        for (int it = 0; it < 2; ++it)
            #pragma unroll
            for (int jp = 0; jp < 2; ++jp)
                #pragma unroll
                for (int reg = 0; reg < 4; ++reg)
                    sm.Tls[jp * 16 + lr][w * 32 + it * 16 + lk * 4 + reg] =
                        acc[it][g * 2 + jp][reg];
        __syncthreads();
        if (bi != bj) {
            #pragma unroll
            for (int r4 = 0; r4 < 4; ++r4) {
                int tr = r4 * 8 + (t >> 5);
                int tc = (t & 31) * 4;
                float4 v = *(const float4*)&sm.Tls[tr][tc];
                *(float4*)&out2[(size_t)(cbase + g * 32 + tr) * NN + rbase + tc] = v;
            }
        }
        // sampling: thread (rr,half) -> 16 bits of word (row rr, chunk g)
        {
            int rr = t >> 1, half = t & 1;
            int r = rbase + rr;
            uint32_t hw = 0;
            #pragma unroll
            for (int e = 0; e < 16; ++e) {
                int cl = half * 16 + e;
                float z = sm.Tls[cl][rr];
                int c = cbase + g * 32 + cl;
                float l = z < Lmin ? Lmin : (z > Lmax ? Lmax : z);
                int lo = r < c ? r : c;
                int hi = r < c ? c : r;
                uint32_t idx = (uint32_t)lo * NN + (uint32_t)hi;
                float u = jax_uniform(jax_bits32(k10, k11, idx));
                float thr = 1.0f / (1.0f + expf(l));
                uint32_t bit = (r == c) ? 1u : (u > thr ? 1u : 0u);
                hw |= bit << e;
            }
            uint32_t p = (uint32_t)__shfl_xor((int)hw, 1);
            if (half == 0) {
                uint32_t word = hw | (p << 16);
                Wl[rr][g] = word;
                mask[(size_t)r * (NN / 32) + (cbase >> 5) + g] = word;
                atomicAdd(&rs_i[rr], (int)__popc(word));
            }
        }
    }
    __syncthreads();
    if (bi != bj) {
        // mirror mask words: bit-transpose of Wl
        int cc = t >> 1;
        #pragma unroll
        for (int wi = 0; wi < 2; ++wi) {
            int wr = (t & 1) * 2 + wi;
            uint32_t tw = 0;
            #pragma unroll
            for (int bb = 0; bb < 32; ++bb)
                tw |= ((Wl[wr * 32 + bb][cc >> 5] >> (cc & 31)) & 1u) << bb;
            mask[(size_t)(cbase + cc) * (NN / 32) + (rbase >> 5) + wr] = tw;
            atomicAdd(&cs_i[cc], (int)__popc(tw));
        }
    }
    __syncthreads();
    if (t < 128) {
        atomicAdd(&rowsum[rbase + t], (float)rs_i[t]);
        if (bi != bj) atomicAdd(&rowsum[cbase + t], (float)cs_i[t]);
    }
}

// expand bitmask -> adj_norm with inline degree: out0[r][c] = bit ? d_r*d_c : 0
__global__ void k_scale3(const uint32_t* __restrict__ mask,
                         const float* __restrict__ rowsum, float* __restrict__ out0) {
    size_t idx = ((size_t)blockIdx.x * 256 + threadIdx.x) * 4;
    int r = (int)(idx >> 12);
    int c = (int)(idx & 4095);
    uint32_t wv = mask[idx >> 5];
    int sh = (int)(idx & 31);
    float dr = 1.0f / sqrtf(rowsum[r]);
    float4 rc = *(const float4*)&rowsum[c];
    float4 o;
    o.x = ((wv >> (sh + 0)) & 1u) ? dr * (1.0f / sqrtf(rc.x)) : 0.0f;
    o.y = ((wv >> (sh + 1)) & 1u) ? dr * (1.0f / sqrtf(rc.y)) : 0.0f;
    o.z = ((wv >> (sh + 2)) & 1u) ? dr * (1.0f / sqrtf(rc.z)) : 0.0f;
    o.w = ((wv >> (sh + 3)) & 1u) ? dr * (1.0f / sqrtf(rc.w)) : 0.0f;
    *(float4*)&out0[idx] = o;
}

// ---------------- launch ----------------
extern "C" void kernel_launch(void* const* d_in, const int* in_sizes, int n_in,
                              void* d_out, int out_size, void* d_ws, size_t ws_size,
                              hipStream_t stream) {
    const float* adj = (const float*)d_in[0];
    const float* x   = (const float*)d_in[1];
    const float* Wg  = (const float*)d_in[2];
    const float* bg  = (const float*)d_in[3];
    const float* Wa1 = (const float*)d_in[4];
    const float* ba1 = (const float*)d_in[5];
    const float* Wa2 = (const float*)d_in[6];
    const float* ba2 = (const float*)d_in[7];
    const float* Wx1 = (const float*)d_in[8];
    const float* bx1 = (const float*)d_in[9];
    const float* Wx2 = (const float*)d_in[10];
    const float* bx2 = (const float*)d_in[11];

    float* out0 = (float*)d_out;                          // adj_norm [N,N]
    float* out1 = out0 + (size_t)NN * NN;                 // x_new [N,F]
    float* out2 = out1 + (size_t)NN * FF;                 // adj_logits [N,N]

    ushort_t* Tt   = (ushort_t*)d_ws;                       // [64,4096] bf16, 512 KB
    float* h       = (float*)((char*)d_ws + (1 << 20));     // (unused, layout kept)
    ushort_t* Zb   = (ushort_t*)(h + NN * HH);              // [4096,512] bf16, 4 MB
    float* partial = (float*)((char*)Zb + (size_t)NN * FF * 2); // [8][4096,64] 8 MB
    float* rowsum  = partial + (size_t)KSPLIT * NN * HH;    // [4096]
    // edge bitmask [4096][128] u32 (2 MB) aliased onto partial
    // (safe: k_mlp consumes partial BEFORE k_zzt_fused writes mask)
    uint32_t* mask = (uint32_t*)partial;

    uint32_t k1a, k1b, k2a, k2b;
    threefry2x32(0u, 42u, 0u, 0u, k1a, k1b);  // adjacency noise key
    threefry2x32(0u, 42u, 0u, 1u, k2a, k2b);  // feature-mask noise key

    const float Lmax = (float)(std::log(1.0 - 1e-6) - std::log1p(-(1.0 - 1e-6)));
    const float Lmin = (float)(std::log(1e-6) - std::log1p(-1e-6));

    k_xw<<<NN / 4, dim3(64, 4), 0, stream>>>(x, Wg, Tt);
    k_adjT_mfma<<<dim3(64, KSPLIT), 256, 0, stream>>>(adj, Tt, partial);
    k_mlp<<<NN / 8, 256, 0, stream>>>(partial, bg, Wa1, ba1, Wa2, ba2,
                                      Wx1, bx1, Wx2, bx2, x, Zb, out1,
                                      k2a, k2b, Lmin, Lmax);

    hipMemsetAsync(rowsum, 0, NN * sizeof(float), stream);
    k_zzt_fused<<<528, 256, 0, stream>>>(Zb, out2, mask, rowsum,
                                         k1a, k1b, Lmin, Lmax);
    k_scale3<<<NN * NN / 4 / 256, 256, 0, stream>>>(mask, rowsum, out0);
}

// Round 8
// 383.406 us; speedup vs baseline: 1.4127x; 1.4127x over previous
//
#include <hip/hip_runtime.h>
#include <cstdint>
#include <cmath>

#define NN 4096
#define FF 512
#define HH 64
#define KSPLIT 8

typedef unsigned short ushort_t;
typedef short bf16x8 __attribute__((ext_vector_type(8)));
typedef float f32x4 __attribute__((ext_vector_type(4)));

// ---------------- threefry2x32 (JAX-compatible, 20 rounds) ----------------
__host__ __device__ __forceinline__ uint32_t rotl32(uint32_t x, int r) {
    return (x << r) | (x >> (32 - r));
}

__host__ __device__ __forceinline__ void threefry2x32(uint32_t ks0, uint32_t ks1,
                                                      uint32_t x0, uint32_t x1,
                                                      uint32_t& o0, uint32_t& o1) {
    uint32_t ks2 = ks0 ^ ks1 ^ 0x1BD11BDAu;
    x0 += ks0; x1 += ks1;
    x0 += x1; x1 = rotl32(x1, 13); x1 ^= x0;
    x0 += x1; x1 = rotl32(x1, 15); x1 ^= x0;
    x0 += x1; x1 = rotl32(x1, 26); x1 ^= x0;
    x0 += x1; x1 = rotl32(x1,  6); x1 ^= x0;
    x0 += ks1; x1 += ks2 + 1u;
    x0 += x1; x1 = rotl32(x1, 17); x1 ^= x0;
    x0 += x1; x1 = rotl32(x1, 29); x1 ^= x0;
    x0 += x1; x1 = rotl32(x1, 16); x1 ^= x0;
    x0 += x1; x1 = rotl32(x1, 24); x1 ^= x0;
    x0 += ks2; x1 += ks0 + 2u;
    x0 += x1; x1 = rotl32(x1, 13); x1 ^= x0;
    x0 += x1; x1 = rotl32(x1, 15); x1 ^= x0;
    x0 += x1; x1 = rotl32(x1, 26); x1 ^= x0;
    x0 += x1; x1 = rotl32(x1,  6); x1 ^= x0;
    x0 += ks0; x1 += ks1 + 3u;
    x0 += x1; x1 = rotl32(x1, 17); x1 ^= x0;
    x0 += x1; x1 = rotl32(x1, 29); x1 ^= x0;
    x0 += x1; x1 = rotl32(x1, 16); x1 ^= x0;
    x0 += x1; x1 = rotl32(x1, 24); x1 ^= x0;
    x0 += ks1; x1 += ks2 + 4u;
    x0 += x1; x1 = rotl32(x1, 13); x1 ^= x0;
    x0 += x1; x1 = rotl32(x1, 15); x1 ^= x0;
    x0 += x1; x1 = rotl32(x1, 26); x1 ^= x0;
    x0 += x1; x1 = rotl32(x1,  6); x1 ^= x0;
    x0 += ks2; x1 += ks0 + 5u;
    o0 = x0; o1 = x1;
}

__device__ __forceinline__ uint32_t jax_bits32(uint32_t k0, uint32_t k1, uint32_t j) {
    uint32_t b0, b1;
    threefry2x32(k0, k1, 0u, j, b0, b1);
    return b0 ^ b1;
}

__device__ __forceinline__ float jax_uniform(uint32_t bits) {
    const float minv = 1e-6f;
    const float maxv = (float)(1.0 - 1e-6);
    const float span = maxv - minv;
    float f = __uint_as_float((bits >> 9) | 0x3f800000u) - 1.0f;
    float u = __fadd_rn(__fmul_rn(f, span), minv);
    return fmaxf(minv, u);
}

// hard Bernoulli-ST forward: 1[ l + logit(u) > 0 ]  <=>  u > 1/(1+e^l)
__device__ __forceinline__ float hard_sample_f(float l, float u) {
    float thr = 1.0f / (1.0f + expf(l));
    return (u > thr) ? 1.0f : 0.0f;
}

__device__ __forceinline__ ushort_t f32_to_bf16_rne(float f) {
    uint32_t x = __float_as_uint(f);
    uint32_t r = (x + 0x7fffu + ((x >> 16) & 1u)) >> 16;
    return (ushort_t)r;
}

// ---------------- pipeline kernels ----------------

// Tt[64,4096] (bf16, transposed) = (x[4096,512] @ Wg[512,64])^T
__global__ void k_xw(const float* __restrict__ x, const float* __restrict__ Wg,
                     ushort_t* __restrict__ Tt) {
    __shared__ ushort_t Tls[4][64];
    int col = threadIdx.x, ty = threadIdx.y;
    int row = blockIdx.x * 4 + ty;
    const float* xr = x + row * FF;
    float acc = 0.0f;
    #pragma unroll 4
    for (int k = 0; k < FF; ++k)
        acc += xr[k] * Wg[k * HH + col];
    Tls[ty][col] = f32_to_bf16_rne(acc);
    __syncthreads();
    int t = ty * 64 + col;
    if (t < 64) {
        uint2 v;
        ushort_t* p = (ushort_t*)&v;
        p[0] = Tls[0][t]; p[1] = Tls[1][t]; p[2] = Tls[2][t]; p[3] = Tls[3][t];
        *(uint2*)&Tt[(size_t)t * NN + blockIdx.x * 4] = v;
    }
}

// partial[s][4096][64] += adj(bf16-cvt)[*,Kslice] @ T[Kslice,*] via MFMA.
__global__ void __launch_bounds__(256)
k_adjT_mfma(const float* __restrict__ adj, const ushort_t* __restrict__ Tt,
            float* __restrict__ partial) {
    __shared__ __align__(16) ushort_t As[64][72];
    __shared__ __align__(16) ushort_t Tl[64][72];
    int t = threadIdx.x;
    int lane = t & 63, w = t >> 6;
    int lr = lane & 15, lk = lane >> 4;
    int r0 = blockIdx.x * 64;
    int kb = blockIdx.y * (NN / KSPLIT);
    f32x4 acc[4] = {};
    for (int k0 = 0; k0 < NN / KSPLIT; k0 += 64) {
        __syncthreads();
        #pragma unroll
        for (int i = 0; i < 4; ++i) {
            int idx = t + i * 256;
            int rr = idx >> 4;
            int kq = (idx & 15) * 4;
            float4 v = *(const float4*)&adj[(size_t)(r0 + rr) * NN + kb + k0 + kq];
            uint32_t lo = (uint32_t)f32_to_bf16_rne(v.x) | ((uint32_t)f32_to_bf16_rne(v.y) << 16);
            uint32_t hi = (uint32_t)f32_to_bf16_rne(v.z) | ((uint32_t)f32_to_bf16_rne(v.w) << 16);
            uint2 pk = {lo, hi};
            *(uint2*)&As[rr][kq] = pk;
        }
        #pragma unroll
        for (int i = 0; i < 2; ++i) {
            int idx = t + i * 256;
            int cc = idx >> 3;
            int kq = (idx & 7) * 8;
            *(uint4*)&Tl[cc][kq] = *(const uint4*)&Tt[(size_t)cc * NN + kb + k0 + kq];
        }
        __syncthreads();
        #pragma unroll
        for (int ks = 0; ks < 2; ++ks) {
            bf16x8 a = *(const bf16x8*)&As[w * 16 + lr][ks * 32 + lk * 8];
            #pragma unroll
            for (int c = 0; c < 4; ++c) {
                bf16x8 bb = *(const bf16x8*)&Tl[c * 16 + lr][ks * 32 + lk * 8];
                acc[c] = __builtin_amdgcn_mfma_f32_16x16x32_bf16(a, bb, acc[c], 0, 0, 0);
            }
        }
    }
    float* P = partial + (size_t)blockIdx.y * NN * HH;
    #pragma unroll
    for (int c = 0; c < 4; ++c)
        #pragma unroll
        for (int reg = 0; reg < 4; ++reg)
            P[(size_t)(r0 + w * 16 + lk * 4 + reg) * HH + c * 16 + lr] = acc[c][reg];
}

// h = relu(sum_s partial[s] + bg)
__global__ void k_hred(const float* __restrict__ partial, const float* __restrict__ bg,
                       float* __restrict__ h) {
    int idx = blockIdx.x * 256 + threadIdx.x;
    float s = 0.0f;
    #pragma unroll
    for (int p = 0; p < KSPLIT; ++p) s += partial[(size_t)p * NN * HH + idx];
    float v = s + bg[idx & (HH - 1)];
    h[idx] = v > 0.0f ? v : 0.0f;
}

// Fused MLPA: Zb[4096,512](bf16) = (relu(h@W1+b1)) @ W2 + b2, 8 rows/block.
__global__ void __launch_bounds__(256)
k_mlpZ(const float* __restrict__ h, const float* __restrict__ W1,
       const float* __restrict__ b1, const float* __restrict__ W2,
       const float* __restrict__ b2, ushort_t* __restrict__ Zb) {
    __shared__ float W1l[HH][HH];
    __shared__ float A1l[8][HH];
    __shared__ float hl[8][HH];
    int t = threadIdx.x;
    int r0 = blockIdx.x * 8;
    for (int n = t; n < HH * HH; n += 256) ((float*)W1l)[n] = W1[n];
    for (int n = t; n < 8 * HH; n += 256) ((float*)hl)[n] = h[r0 * HH + n];
    __syncthreads();
    {
        int col = t & 63;
        int rb = t >> 6;
        #pragma unroll
        for (int rr = 0; rr < 2; ++rr) {
            int row = rb * 2 + rr;
            float acc = b1[col];
            #pragma unroll
            for (int k = 0; k < HH; ++k) acc += hl[row][k] * W1l[k][col];
            A1l[row][col] = acc > 0.0f ? acc : 0.0f;
        }
    }
    __syncthreads();
    #pragma unroll
    for (int p = 0; p < 2; ++p) {
        int col = p * 256 + t;
        float wc[HH];
        #pragma unroll
        for (int k = 0; k < HH; ++k) wc[k] = W2[k * FF + col];
        float bb = b2[col];
        #pragma unroll
        for (int row = 0; row < 8; ++row) {
            float acc = bb;
            #pragma unroll
            for (int k = 0; k < HH; ++k) acc += A1l[row][k] * wc[k];
            Zb[(size_t)(r0 + row) * FF + col] = f32_to_bf16_rne(acc);
        }
    }
}

// Fused MLPX + feature-mask sampling: xnew = x * mask(relu(h@Wx1+bx1)@Wx2+bx2)
__global__ void __launch_bounds__(256)
k_mlpM(const float* __restrict__ h, const float* __restrict__ W1,
       const float* __restrict__ b1, const float* __restrict__ W2,
       const float* __restrict__ b2, const float* __restrict__ x,
       float* __restrict__ xnew, uint32_t k20, uint32_t k21,
       float Lmin, float Lmax) {
    __shared__ float W1l[HH][HH];
    __shared__ float A1l[8][HH];
    __shared__ float hl[8][HH];
    int t = threadIdx.x;
    int r0 = blockIdx.x * 8;
    for (int n = t; n < HH * HH; n += 256) ((float*)W1l)[n] = W1[n];
    for (int n = t; n < 8 * HH; n += 256) ((float*)hl)[n] = h[r0 * HH + n];
    __syncthreads();
    {
        int col = t & 63;
        int rb = t >> 6;
        #pragma unroll
        for (int rr = 0; rr < 2; ++rr) {
            int row = rb * 2 + rr;
            float acc = b1[col];
            #pragma unroll
            for (int k = 0; k < HH; ++k) acc += hl[row][k] * W1l[k][col];
            A1l[row][col] = acc > 0.0f ? acc : 0.0f;
        }
    }
    __syncthreads();
    #pragma unroll
    for (int p = 0; p < 2; ++p) {
        int col = p * 256 + t;
        float wc[HH];
        #pragma unroll
        for (int k = 0; k < HH; ++k) wc[k] = W2[k * FF + col];
        float bb = b2[col];
        #pragma unroll
        for (int row = 0; row < 8; ++row) {
            float acc = bb;
            #pragma unroll
            for (int k = 0; k < HH; ++k) acc += A1l[row][k] * wc[k];
            float ml = acc;
            float l = ml < Lmin ? Lmin : (ml > Lmax ? Lmax : ml);
            uint32_t idx = (uint32_t)(r0 + row) * FF + (uint32_t)col;
            float u = jax_uniform(jax_bits32(k20, k21, idx));
            float m = hard_sample_f(l, u);
            size_t gi = (size_t)(r0 + row) * FF + col;
            xnew[gi] = (m != 0.0f) ? x[gi] : 0.0f;
        }
    }
}

// adj_logits = Zb @ Zb^T (bf16 MFMA, triangular 528 blocks) + FUSED sampling.
// Known-good round-6 form: 2-barrier staging loop (compiler-scheduled),
// all acc indices compile-time constant (rule #20). Do NOT add VGPR
// prefetch here: 64 acc + 32 prefetch regs => scratch spill (round-7,
// VGPR 76 / +60 MB spill traffic / 168 µs vs 66 µs).
__global__ void __launch_bounds__(256)
k_zzt_fused(const ushort_t* __restrict__ Zb, float* __restrict__ out2,
            uint32_t* __restrict__ mask, float* __restrict__ rowsum,
            uint32_t k10, uint32_t k11, float Lmin, float Lmax) {
    __shared__ __align__(16) union {
        struct { ushort_t At[128][72]; ushort_t Bt[128][72]; } s;  // 36.9 KB
        float Tls[32][132];                                         // 16.9 KB
    } sm;
    __shared__ uint32_t Wl[128][5];
    __shared__ int rs_i[128], cs_i[128];
    int t = threadIdx.x;
    int lane = t & 63, w = t >> 6;
    int lr = lane & 15, lk = lane >> 4;
    if (t < 128) { rs_i[t] = 0; cs_i[t] = 0; }
    int b = blockIdx.x, bi = 0;
    while (b >= 32 - bi) { b -= 32 - bi; ++bi; }
    int bj = bi + b;
    int rbase = bi * 128, cbase = bj * 128;
    f32x4 acc[2][8] = {};
    for (int k0 = 0; k0 < FF; k0 += 64) {
        __syncthreads();
        for (int n = t; n < 1024; n += 256) {
            int rr = n >> 3, ck = n & 7;
            *(uint4*)&sm.s.At[rr][ck * 8] = *(const uint4*)&Zb[(size_t)(rbase + rr) * FF + k0 + ck * 8];
            *(uint4*)&sm.s.Bt[rr][ck * 8] = *(const uint4*)&Zb[(size_t)(cbase + rr) * FF + k0 + ck * 8];
        }
        __syncthreads();
        #pragma unroll
        for (int ks = 0; ks < 2; ++ks) {
            bf16x8 a0 = *(const bf16x8*)&sm.s.At[w * 32 + lr][ks * 32 + lk * 8];
            bf16x8 a1 = *(const bf16x8*)&sm.s.At[w * 32 + 16 + lr][ks * 32 + lk * 8];
            #pragma unroll
            for (int j = 0; j < 8; ++j) {
                bf16x8 bb = *(const bf16x8*)&sm.s.Bt[j * 16 + lr][ks * 32 + lk * 8];
                acc[0][j] = __builtin_amdgcn_mfma_f32_16x16x32_bf16(a0, bb, acc[0][j], 0, 0, 0);
                acc[1][j] = __builtin_amdgcn_mfma_f32_16x16x32_bf16(a1, bb, acc[1][j], 0, 0, 0);
            }
        }
    }
    // direct (bi,bj) tile store — row-major coalesced
    #pragma unroll
    for (int it = 0; it < 2; ++it) {
        int rg = rbase + w * 32 + it * 16 + lk * 4;
        #pragma unroll
        for (int reg = 0; reg < 4; ++reg)
            #pragma unroll
            for (int j = 0; j < 8; ++j)
                out2[(size_t)(rg + reg) * NN + cbase + j * 16 + lr] = acc[it][j][reg];
    }
    // 4 col-chunks: mirror-transpose store (off-diag) + fused sampling (all).
    // FULL unroll: acc indices must stay compile-time constant (rule #20).
    #pragma unroll
    for (int g = 0; g < 4; ++g) {
        __syncthreads();
        #pragma unroll
        for (int it = 0; it < 2; ++it)
            #pragma unroll
            for (int jp = 0; jp < 2; ++jp)
                #pragma unroll
                for (int reg = 0; reg < 4; ++reg)
                    sm.Tls[jp * 16 + lr][w * 32 + it * 16 + lk * 4 + reg] =
                        acc[it][g * 2 + jp][reg];
        __syncthreads();
        if (bi != bj) {
            #pragma unroll
            for (int r4 = 0; r4 < 4; ++r4) {
                int tr = r4 * 8 + (t >> 5);
                int tc = (t & 31) * 4;
                float4 v = *(const float4*)&sm.Tls[tr][tc];
                *(float4*)&out2[(size_t)(cbase + g * 32 + tr) * NN + rbase + tc] = v;
            }
        }
        // sampling: thread (rr,half) -> 16 bits of word (row rr, chunk g)
        {
            int rr = t >> 1, half = t & 1;
            int r = rbase + rr;
            uint32_t hw = 0;
            #pragma unroll
            for (int e = 0; e < 16; ++e) {
                int cl = half * 16 + e;
                float z = sm.Tls[cl][rr];
                int c = cbase + g * 32 + cl;
                float l = z < Lmin ? Lmin : (z > Lmax ? Lmax : z);
                int lo = r < c ? r : c;
                int hi = r < c ? c : r;
                uint32_t idx = (uint32_t)lo * NN + (uint32_t)hi;
                float u = jax_uniform(jax_bits32(k10, k11, idx));
                float thr = 1.0f / (1.0f + expf(l));
                uint32_t bit = (r == c) ? 1u : (u > thr ? 1u : 0u);
                hw |= bit << e;
            }
            uint32_t p = (uint32_t)__shfl_xor((int)hw, 1);
            if (half == 0) {
                uint32_t word = hw | (p << 16);
                Wl[rr][g] = word;
                mask[(size_t)r * (NN / 32) + (cbase >> 5) + g] = word;
                atomicAdd(&rs_i[rr], (int)__popc(word));
            }
        }
    }
    __syncthreads();
    if (bi != bj) {
        // mirror mask words: bit-transpose of Wl (as verified k_sample_tri)
        int cc = t >> 1;
        #pragma unroll
        for (int wi = 0; wi < 2; ++wi) {
            int wr = (t & 1) * 2 + wi;
            uint32_t tw = 0;
            #pragma unroll
            for (int bb = 0; bb < 32; ++bb)
                tw |= ((Wl[wr * 32 + bb][cc >> 5] >> (cc & 31)) & 1u) << bb;
            mask[(size_t)(cbase + cc) * (NN / 32) + (rbase >> 5) + wr] = tw;
            atomicAdd(&cs_i[cc], (int)__popc(tw));
        }
    }
    __syncthreads();
    if (t < 128) {
        atomicAdd(&rowsum[rbase + t], (float)rs_i[t]);
        if (bi != bj) atomicAdd(&rowsum[cbase + t], (float)cs_i[t]);
    }
}

// expand bitmask -> adj_norm with inline degree: out0[r][c] = bit ? d_r*d_c : 0
__global__ void k_scale3(const uint32_t* __restrict__ mask,
                         const float* __restrict__ rowsum, float* __restrict__ out0) {
    size_t idx = ((size_t)blockIdx.x * 256 + threadIdx.x) * 4;
    int r = (int)(idx >> 12);
    int c = (int)(idx & 4095);
    uint32_t wv = mask[idx >> 5];
    int sh = (int)(idx & 31);
    float dr = 1.0f / sqrtf(rowsum[r]);
    float4 rc = *(const float4*)&rowsum[c];
    float4 o;
    o.x = ((wv >> (sh + 0)) & 1u) ? dr * (1.0f / sqrtf(rc.x)) : 0.0f;
    o.y = ((wv >> (sh + 1)) & 1u) ? dr * (1.0f / sqrtf(rc.y)) : 0.0f;
    o.z = ((wv >> (sh + 2)) & 1u) ? dr * (1.0f / sqrtf(rc.z)) : 0.0f;
    o.w = ((wv >> (sh + 3)) & 1u) ? dr * (1.0f / sqrtf(rc.w)) : 0.0f;
    *(float4*)&out0[idx] = o;
}

// ---------------- launch ----------------
extern "C" void kernel_launch(void* const* d_in, const int* in_sizes, int n_in,
                              void* d_out, int out_size, void* d_ws, size_t ws_size,
                              hipStream_t stream) {
    const float* adj = (const float*)d_in[0];
    const float* x   = (const float*)d_in[1];
    const float* Wg  = (const float*)d_in[2];
    const float* bg  = (const float*)d_in[3];
    const float* Wa1 = (const float*)d_in[4];
    const float* ba1 = (const float*)d_in[5];
    const float* Wa2 = (const float*)d_in[6];
    const float* ba2 = (const float*)d_in[7];
    const float* Wx1 = (const float*)d_in[8];
    const float* bx1 = (const float*)d_in[9];
    const float* Wx2 = (const float*)d_in[10];
    const float* bx2 = (const float*)d_in[11];

    float* out0 = (float*)d_out;                          // adj_norm [N,N]
    float* out1 = out0 + (size_t)NN * NN;                 // x_new [N,F]
    float* out2 = out1 + (size_t)NN * FF;                 // adj_logits [N,N]

    ushort_t* Tt   = (ushort_t*)d_ws;                       // [64,4096] bf16, 512 KB
    float* h       = (float*)((char*)d_ws + (1 << 20));     // [4096,64]  1 MB
    ushort_t* Zb   = (ushort_t*)(h + NN * HH);              // [4096,512] bf16, 4 MB
    float* partial = (float*)((char*)Zb + (size_t)NN * FF * 2); // [8][4096,64] 8 MB
    float* rowsum  = partial + (size_t)KSPLIT * NN * HH;    // [4096]
    // edge bitmask [4096][128] u32 (2 MB) aliased onto partial (dead after k_hred)
    uint32_t* mask = (uint32_t*)partial;

    uint32_t k1a, k1b, k2a, k2b;
    threefry2x32(0u, 42u, 0u, 0u, k1a, k1b);  // adjacency noise key
    threefry2x32(0u, 42u, 0u, 1u, k2a, k2b);  // feature-mask noise key

    const float Lmax = (float)(std::log(1.0 - 1e-6) - std::log1p(-(1.0 - 1e-6)));
    const float Lmin = (float)(std::log(1e-6) - std::log1p(-1e-6));

    k_xw<<<NN / 4, dim3(64, 4), 0, stream>>>(x, Wg, Tt);
    k_adjT_mfma<<<dim3(64, KSPLIT), 256, 0, stream>>>(adj, Tt, partial);
    k_hred<<<NN * HH / 256, 256, 0, stream>>>(partial, bg, h);
    k_mlpZ<<<NN / 8, 256, 0, stream>>>(h, Wa1, ba1, Wa2, ba2, Zb);

    hipMemsetAsync(rowsum, 0, NN * sizeof(float), stream);
    k_zzt_fused<<<528, 256, 0, stream>>>(Zb, out2, mask, rowsum,
                                         k1a, k1b, Lmin, Lmax);
    k_scale3<<<NN * NN / 4 / 256, 256, 0, stream>>>(mask, rowsum, out0);

    k_mlpM<<<NN / 8, 256, 0, stream>>>(h, Wx1, bx1, Wx2, bx2, x, out1,
                                       k2a, k2b, Lmin, Lmax);
}

// Round 9
// 380.085 us; speedup vs baseline: 1.4250x; 1.0087x over previous
//
#include <hip/hip_runtime.h>
#include <cstdint>
#include <cmath>

#define NN 4096
#define FF 512
#define HH 64
#define KSPLIT 8

typedef unsigned short ushort_t;
typedef short bf16x8 __attribute__((ext_vector_type(8)));
typedef float f32x4 __attribute__((ext_vector_type(4)));

// ---------------- threefry2x32 (JAX-compatible, 20 rounds) ----------------
__host__ __device__ __forceinline__ uint32_t rotl32(uint32_t x, int r) {
    return (x << r) | (x >> (32 - r));
}

__host__ __device__ __forceinline__ void threefry2x32(uint32_t ks0, uint32_t ks1,
                                                      uint32_t x0, uint32_t x1,
                                                      uint32_t& o0, uint32_t& o1) {
    uint32_t ks2 = ks0 ^ ks1 ^ 0x1BD11BDAu;
    x0 += ks0; x1 += ks1;
    x0 += x1; x1 = rotl32(x1, 13); x1 ^= x0;
    x0 += x1; x1 = rotl32(x1, 15); x1 ^= x0;
    x0 += x1; x1 = rotl32(x1, 26); x1 ^= x0;
    x0 += x1; x1 = rotl32(x1,  6); x1 ^= x0;
    x0 += ks1; x1 += ks2 + 1u;
    x0 += x1; x1 = rotl32(x1, 17); x1 ^= x0;
    x0 += x1; x1 = rotl32(x1, 29); x1 ^= x0;
    x0 += x1; x1 = rotl32(x1, 16); x1 ^= x0;
    x0 += x1; x1 = rotl32(x1, 24); x1 ^= x0;
    x0 += ks2; x1 += ks0 + 2u;
    x0 += x1; x1 = rotl32(x1, 13); x1 ^= x0;
    x0 += x1; x1 = rotl32(x1, 15); x1 ^= x0;
    x0 += x1; x1 = rotl32(x1, 26); x1 ^= x0;
    x0 += x1; x1 = rotl32(x1,  6); x1 ^= x0;
    x0 += ks0; x1 += ks1 + 3u;
    x0 += x1; x1 = rotl32(x1, 17); x1 ^= x0;
    x0 += x1; x1 = rotl32(x1, 29); x1 ^= x0;
    x0 += x1; x1 = rotl32(x1, 16); x1 ^= x0;
    x0 += x1; x1 = rotl32(x1, 24); x1 ^= x0;
    x0 += ks1; x1 += ks2 + 4u;
    x0 += x1; x1 = rotl32(x1, 13); x1 ^= x0;
    x0 += x1; x1 = rotl32(x1, 15); x1 ^= x0;
    x0 += x1; x1 = rotl32(x1, 26); x1 ^= x0;
    x0 += x1; x1 = rotl32(x1,  6); x1 ^= x0;
    x0 += ks2; x1 += ks0 + 5u;
    o0 = x0; o1 = x1;
}

__device__ __forceinline__ uint32_t jax_bits32(uint32_t k0, uint32_t k1, uint32_t j) {
    uint32_t b0, b1;
    threefry2x32(k0, k1, 0u, j, b0, b1);
    return b0 ^ b1;
}

__device__ __forceinline__ float jax_uniform(uint32_t bits) {
    const float minv = 1e-6f;
    const float maxv = (float)(1.0 - 1e-6);
    const float span = maxv - minv;
    float f = __uint_as_float((bits >> 9) | 0x3f800000u) - 1.0f;
    float u = __fadd_rn(__fmul_rn(f, span), minv);
    return fmaxf(minv, u);
}

// hard Bernoulli-ST forward: 1[ l + logit(u) > 0 ]  <=>  u > 1/(1+e^l)
__device__ __forceinline__ float hard_sample_f(float l, float u) {
    float thr = 1.0f / (1.0f + expf(l));
    return (u > thr) ? 1.0f : 0.0f;
}

__device__ __forceinline__ ushort_t f32_to_bf16_rne(float f) {
    uint32_t x = __float_as_uint(f);
    uint32_t r = (x + 0x7fffu + ((x >> 16) & 1u)) >> 16;
    return (ushort_t)r;
}

// ---------------- pipeline kernels ----------------

// Tt[64,4096] (bf16, transposed) = (x[4096,512] @ Wg[512,64])^T
__global__ void k_xw(const float* __restrict__ x, const float* __restrict__ Wg,
                     ushort_t* __restrict__ Tt) {
    __shared__ ushort_t Tls[4][64];
    int col = threadIdx.x, ty = threadIdx.y;
    int row = blockIdx.x * 4 + ty;
    const float* xr = x + row * FF;
    float acc = 0.0f;
    #pragma unroll 4
    for (int k = 0; k < FF; ++k)
        acc += xr[k] * Wg[k * HH + col];
    Tls[ty][col] = f32_to_bf16_rne(acc);
    __syncthreads();
    int t = ty * 64 + col;
    if (t < 64) {
        uint2 v;
        ushort_t* p = (ushort_t*)&v;
        p[0] = Tls[0][t]; p[1] = Tls[1][t]; p[2] = Tls[2][t]; p[3] = Tls[3][t];
        *(uint2*)&Tt[(size_t)t * NN + blockIdx.x * 4] = v;
    }
}

// partial[s][4096][64] += adj(bf16-cvt)[*,Kslice] @ T[Kslice,*] via MFMA.
// T5: setprio(1) around the MFMA cluster — co-resident blocks alternate
// staging-cvt (VALU) and MFMA phases, so priority favors the matrix pipe.
__global__ void __launch_bounds__(256)
k_adjT_mfma(const float* __restrict__ adj, const ushort_t* __restrict__ Tt,
            float* __restrict__ partial) {
    __shared__ __align__(16) ushort_t As[64][72];
    __shared__ __align__(16) ushort_t Tl[64][72];
    int t = threadIdx.x;
    int lane = t & 63, w = t >> 6;
    int lr = lane & 15, lk = lane >> 4;
    int r0 = blockIdx.x * 64;
    int kb = blockIdx.y * (NN / KSPLIT);
    f32x4 acc[4] = {};
    for (int k0 = 0; k0 < NN / KSPLIT; k0 += 64) {
        __syncthreads();
        #pragma unroll
        for (int i = 0; i < 4; ++i) {
            int idx = t + i * 256;
            int rr = idx >> 4;
            int kq = (idx & 15) * 4;
            float4 v = *(const float4*)&adj[(size_t)(r0 + rr) * NN + kb + k0 + kq];
            uint32_t lo = (uint32_t)f32_to_bf16_rne(v.x) | ((uint32_t)f32_to_bf16_rne(v.y) << 16);
            uint32_t hi = (uint32_t)f32_to_bf16_rne(v.z) | ((uint32_t)f32_to_bf16_rne(v.w) << 16);
            uint2 pk = {lo, hi};
            *(uint2*)&As[rr][kq] = pk;
        }
        #pragma unroll
        for (int i = 0; i < 2; ++i) {
            int idx = t + i * 256;
            int cc = idx >> 3;
            int kq = (idx & 7) * 8;
            *(uint4*)&Tl[cc][kq] = *(const uint4*)&Tt[(size_t)cc * NN + kb + k0 + kq];
        }
        __syncthreads();
        __builtin_amdgcn_s_setprio(1);
        #pragma unroll
        for (int ks = 0; ks < 2; ++ks) {
            bf16x8 a = *(const bf16x8*)&As[w * 16 + lr][ks * 32 + lk * 8];
            #pragma unroll
            for (int c = 0; c < 4; ++c) {
                bf16x8 bb = *(const bf16x8*)&Tl[c * 16 + lr][ks * 32 + lk * 8];
                acc[c] = __builtin_amdgcn_mfma_f32_16x16x32_bf16(a, bb, acc[c], 0, 0, 0);
            }
        }
        __builtin_amdgcn_s_setprio(0);
    }
    float* P = partial + (size_t)blockIdx.y * NN * HH;
    #pragma unroll
    for (int c = 0; c < 4; ++c)
        #pragma unroll
        for (int reg = 0; reg < 4; ++reg)
            P[(size_t)(r0 + w * 16 + lk * 4 + reg) * HH + c * 16 + lr] = acc[c][reg];
}

// h = relu(sum_s partial[s] + bg)
__global__ void k_hred(const float* __restrict__ partial, const float* __restrict__ bg,
                       float* __restrict__ h) {
    int idx = blockIdx.x * 256 + threadIdx.x;
    float s = 0.0f;
    #pragma unroll
    for (int p = 0; p < KSPLIT; ++p) s += partial[(size_t)p * NN * HH + idx];
    float v = s + bg[idx & (HH - 1)];
    h[idx] = v > 0.0f ? v : 0.0f;
}

// Fused MLPA: Zb[4096,512](bf16) = (relu(h@W1+b1)) @ W2 + b2, 8 rows/block.
__global__ void __launch_bounds__(256)
k_mlpZ(const float* __restrict__ h, const float* __restrict__ W1,
       const float* __restrict__ b1, const float* __restrict__ W2,
       const float* __restrict__ b2, ushort_t* __restrict__ Zb) {
    __shared__ float W1l[HH][HH];
    __shared__ float A1l[8][HH];
    __shared__ float hl[8][HH];
    int t = threadIdx.x;
    int r0 = blockIdx.x * 8;
    for (int n = t; n < HH * HH; n += 256) ((float*)W1l)[n] = W1[n];
    for (int n = t; n < 8 * HH; n += 256) ((float*)hl)[n] = h[r0 * HH + n];
    __syncthreads();
    {
        int col = t & 63;
        int rb = t >> 6;
        #pragma unroll
        for (int rr = 0; rr < 2; ++rr) {
            int row = rb * 2 + rr;
            float acc = b1[col];
            #pragma unroll
            for (int k = 0; k < HH; ++k) acc += hl[row][k] * W1l[k][col];
            A1l[row][col] = acc > 0.0f ? acc : 0.0f;
        }
    }
    __syncthreads();
    #pragma unroll
    for (int p = 0; p < 2; ++p) {
        int col = p * 256 + t;
        float wc[HH];
        #pragma unroll
        for (int k = 0; k < HH; ++k) wc[k] = W2[k * FF + col];
        float bb = b2[col];
        #pragma unroll
        for (int row = 0; row < 8; ++row) {
            float acc = bb;
            #pragma unroll
            for (int k = 0; k < HH; ++k) acc += A1l[row][k] * wc[k];
            Zb[(size_t)(r0 + row) * FF + col] = f32_to_bf16_rne(acc);
        }
    }
}

// Fused MLPX + feature-mask sampling: xnew = x * mask(relu(h@Wx1+bx1)@Wx2+bx2)
__global__ void __launch_bounds__(256)
k_mlpM(const float* __restrict__ h, const float* __restrict__ W1,
       const float* __restrict__ b1, const float* __restrict__ W2,
       const float* __restrict__ b2, const float* __restrict__ x,
       float* __restrict__ xnew, uint32_t k20, uint32_t k21,
       float Lmin, float Lmax) {
    __shared__ float W1l[HH][HH];
    __shared__ float A1l[8][HH];
    __shared__ float hl[8][HH];
    int t = threadIdx.x;
    int r0 = blockIdx.x * 8;
    for (int n = t; n < HH * HH; n += 256) ((float*)W1l)[n] = W1[n];
    for (int n = t; n < 8 * HH; n += 256) ((float*)hl)[n] = h[r0 * HH + n];
    __syncthreads();
    {
        int col = t & 63;
        int rb = t >> 6;
        #pragma unroll
        for (int rr = 0; rr < 2; ++rr) {
            int row = rb * 2 + rr;
            float acc = b1[col];
            #pragma unroll
            for (int k = 0; k < HH; ++k) acc += hl[row][k] * W1l[k][col];
            A1l[row][col] = acc > 0.0f ? acc : 0.0f;
        }
    }
    __syncthreads();
    #pragma unroll
    for (int p = 0; p < 2; ++p) {
        int col = p * 256 + t;
        float wc[HH];
        #pragma unroll
        for (int k = 0; k < HH; ++k) wc[k] = W2[k * FF + col];
        float bb = b2[col];
        #pragma unroll
        for (int row = 0; row < 8; ++row) {
            float acc = bb;
            #pragma unroll
            for (int k = 0; k < HH; ++k) acc += A1l[row][k] * wc[k];
            float ml = acc;
            float l = ml < Lmin ? Lmin : (ml > Lmax ? Lmax : ml);
            uint32_t idx = (uint32_t)(r0 + row) * FF + (uint32_t)col;
            float u = jax_uniform(jax_bits32(k20, k21, idx));
            float m = hard_sample_f(l, u);
            size_t gi = (size_t)(r0 + row) * FF + col;
            xnew[gi] = (m != 0.0f) ? x[gi] : 0.0f;
        }
    }
}

// adj_logits = Zb @ Zb^T (bf16 MFMA, triangular 528 blocks) + FUSED sampling.
// Known-good round-6 form + T5 setprio around the MFMA cluster (zero-VGPR;
// co-resident blocks are at different phases — GEMM vs threefry epilogue —
// so priority lets MFMA waves win issue slots, the attn-like T5 regime).
// Do NOT add VGPR prefetch (round-7 spill: VGPR 76, +60 MB, 168 µs) and
// keep all acc indices compile-time constant (round-5 spill, rule #20).
__global__ void __launch_bounds__(256)
k_zzt_fused(const ushort_t* __restrict__ Zb, float* __restrict__ out2,
            uint32_t* __restrict__ mask, float* __restrict__ rowsum,
            uint32_t k10, uint32_t k11, float Lmin, float Lmax) {
    __shared__ __align__(16) union {
        struct { ushort_t At[128][72]; ushort_t Bt[128][72]; } s;  // 36.9 KB
        float Tls[32][132];                                         // 16.9 KB
    } sm;
    __shared__ uint32_t Wl[128][5];
    __shared__ int rs_i[128], cs_i[128];
    int t = threadIdx.x;
    int lane = t & 63, w = t >> 6;
    int lr = lane & 15, lk = lane >> 4;
    if (t < 128) { rs_i[t] = 0; cs_i[t] = 0; }
    int b = blockIdx.x, bi = 0;
    while (b >= 32 - bi) { b -= 32 - bi; ++bi; }
    int bj = bi + b;
    int rbase = bi * 128, cbase = bj * 128;
    f32x4 acc[2][8] = {};
    for (int k0 = 0; k0 < FF; k0 += 64) {
        __syncthreads();
        for (int n = t; n < 1024; n += 256) {
            int rr = n >> 3, ck = n & 7;
            *(uint4*)&sm.s.At[rr][ck * 8] = *(const uint4*)&Zb[(size_t)(rbase + rr) * FF + k0 + ck * 8];
            *(uint4*)&sm.s.Bt[rr][ck * 8] = *(const uint4*)&Zb[(size_t)(cbase + rr) * FF + k0 + ck * 8];
        }
        __syncthreads();
        __builtin_amdgcn_s_setprio(1);
        #pragma unroll
        for (int ks = 0; ks < 2; ++ks) {
            bf16x8 a0 = *(const bf16x8*)&sm.s.At[w * 32 + lr][ks * 32 + lk * 8];
            bf16x8 a1 = *(const bf16x8*)&sm.s.At[w * 32 + 16 + lr][ks * 32 + lk * 8];
            #pragma unroll
            for (int j = 0; j < 8; ++j) {
                bf16x8 bb = *(const bf16x8*)&sm.s.Bt[j * 16 + lr][ks * 32 + lk * 8];
                acc[0][j] = __builtin_amdgcn_mfma_f32_16x16x32_bf16(a0, bb, acc[0][j], 0, 0, 0);
                acc[1][j] = __builtin_amdgcn_mfma_f32_16x16x32_bf16(a1, bb, acc[1][j], 0, 0, 0);
            }
        }
        __builtin_amdgcn_s_setprio(0);
    }
    // direct (bi,bj) tile store — row-major coalesced
    #pragma unroll
    for (int it = 0; it < 2; ++it) {
        int rg = rbase + w * 32 + it * 16 + lk * 4;
        #pragma unroll
        for (int reg = 0; reg < 4; ++reg)
            #pragma unroll
            for (int j = 0; j < 8; ++j)
                out2[(size_t)(rg + reg) * NN + cbase + j * 16 + lr] = acc[it][j][reg];
    }
    // 4 col-chunks: mirror-transpose store (off-diag) + fused sampling (all).
    // FULL unroll: acc indices must stay compile-time constant (rule #20).
    #pragma unroll
    for (int g = 0; g < 4; ++g) {
        __syncthreads();
        #pragma unroll
        for (int it = 0; it < 2; ++it)
            #pragma unroll
            for (int jp = 0; jp < 2; ++jp)
                #pragma unroll
                for (int reg = 0; reg < 4; ++reg)
                    sm.Tls[jp * 16 + lr][w * 32 + it * 16 + lk * 4 + reg] =
                        acc[it][g * 2 + jp][reg];
        __syncthreads();
        if (bi != bj) {
            #pragma unroll
            for (int r4 = 0; r4 < 4; ++r4) {
                int tr = r4 * 8 + (t >> 5);
                int tc = (t & 31) * 4;
                float4 v = *(const float4*)&sm.Tls[tr][tc];
                *(float4*)&out2[(size_t)(cbase + g * 32 + tr) * NN + rbase + tc] = v;
            }
        }
        // sampling: thread (rr,half) -> 16 bits of word (row rr, chunk g)
        {
            int rr = t >> 1, half = t & 1;
            int r = rbase + rr;
            uint32_t hw = 0;
            #pragma unroll
            for (int e = 0; e < 16; ++e) {
                int cl = half * 16 + e;
                float z = sm.Tls[cl][rr];
                int c = cbase + g * 32 + cl;
                float l = z < Lmin ? Lmin : (z > Lmax ? Lmax : z);
                int lo = r < c ? r : c;
                int hi = r < c ? c : r;
                uint32_t idx = (uint32_t)lo * NN + (uint32_t)hi;
                float u = jax_uniform(jax_bits32(k10, k11, idx));
                float thr = 1.0f / (1.0f + expf(l));
                uint32_t bit = (r == c) ? 1u : (u > thr ? 1u : 0u);
                hw |= bit << e;
            }
            uint32_t p = (uint32_t)__shfl_xor((int)hw, 1);
            if (half == 0) {
                uint32_t word = hw | (p << 16);
                Wl[rr][g] = word;
                mask[(size_t)r * (NN / 32) + (cbase >> 5) + g] = word;
                atomicAdd(&rs_i[rr], (int)__popc(word));
            }
        }
    }
    __syncthreads();
    if (bi != bj) {
        // mirror mask words: bit-transpose of Wl (as verified k_sample_tri)
        int cc = t >> 1;
        #pragma unroll
        for (int wi = 0; wi < 2; ++wi) {
            int wr = (t & 1) * 2 + wi;
            uint32_t tw = 0;
            #pragma unroll
            for (int bb = 0; bb < 32; ++bb)
                tw |= ((Wl[wr * 32 + bb][cc >> 5] >> (cc & 31)) & 1u) << bb;
            mask[(size_t)(cbase + cc) * (NN / 32) + (rbase >> 5) + wr] = tw;
            atomicAdd(&cs_i[cc], (int)__popc(tw));
        }
    }
    __syncthreads();
    if (t < 128) {
        atomicAdd(&rowsum[rbase + t], (float)rs_i[t]);
        if (bi != bj) atomicAdd(&rowsum[cbase + t], (float)cs_i[t]);
    }
}

// expand bitmask -> adj_norm with inline degree: out0[r][c] = bit ? d_r*d_c : 0
__global__ void k_scale3(const uint32_t* __restrict__ mask,
                         const float* __restrict__ rowsum, float* __restrict__ out0) {
    size_t idx = ((size_t)blockIdx.x * 256 + threadIdx.x) * 4;
    int r = (int)(idx >> 12);
    int c = (int)(idx & 4095);
    uint32_t wv = mask[idx >> 5];
    int sh = (int)(idx & 31);
    float dr = 1.0f / sqrtf(rowsum[r]);
    float4 rc = *(const float4*)&rowsum[c];
    float4 o;
    o.x = ((wv >> (sh + 0)) & 1u) ? dr * (1.0f / sqrtf(rc.x)) : 0.0f;
    o.y = ((wv >> (sh + 1)) & 1u) ? dr * (1.0f / sqrtf(rc.y)) : 0.0f;
    o.z = ((wv >> (sh + 2)) & 1u) ? dr * (1.0f / sqrtf(rc.z)) : 0.0f;
    o.w = ((wv >> (sh + 3)) & 1u) ? dr * (1.0f / sqrtf(rc.w)) : 0.0f;
    *(float4*)&out0[idx] = o;
}

// ---------------- launch ----------------
extern "C" void kernel_launch(void* const* d_in, const int* in_sizes, int n_in,
                              void* d_out, int out_size, void* d_ws, size_t ws_size,
                              hipStream_t stream) {
    const float* adj = (const float*)d_in[0];
    const float* x   = (const float*)d_in[1];
    const float* Wg  = (const float*)d_in[2];
    const float* bg  = (const float*)d_in[3];
    const float* Wa1 = (const float*)d_in[4];
    const float* ba1 = (const float*)d_in[5];
    const float* Wa2 = (const float*)d_in[6];
    const float* ba2 = (const float*)d_in[7];
    const float* Wx1 = (const float*)d_in[8];
    const float* bx1 = (const float*)d_in[9];
    const float* Wx2 = (const float*)d_in[10];
    const float* bx2 = (const float*)d_in[11];

    float* out0 = (float*)d_out;                          // adj_norm [N,N]
    float* out1 = out0 + (size_t)NN * NN;                 // x_new [N,F]
    float* out2 = out1 + (size_t)NN * FF;                 // adj_logits [N,N]

    ushort_t* Tt   = (ushort_t*)d_ws;                       // [64,4096] bf16, 512 KB
    float* h       = (float*)((char*)d_ws + (1 << 20));     // [4096,64]  1 MB
    ushort_t* Zb   = (ushort_t*)(h + NN * HH);              // [4096,512] bf16, 4 MB
    float* partial = (float*)((char*)Zb + (size_t)NN * FF * 2); // [8][4096,64] 8 MB
    float* rowsum  = partial + (size_t)KSPLIT * NN * HH;    // [4096]
    // edge bitmask [4096][128] u32 (2 MB) aliased onto partial (dead after k_hred)
    uint32_t* mask = (uint32_t*)partial;

    uint32_t k1a, k1b, k2a, k2b;
    threefry2x32(0u, 42u, 0u, 0u, k1a, k1b);  // adjacency noise key
    threefry2x32(0u, 42u, 0u, 1u, k2a, k2b);  // feature-mask noise key

    const float Lmax = (float)(std::log(1.0 - 1e-6) - std::log1p(-(1.0 - 1e-6)));
    const float Lmin = (float)(std::log(1e-6) - std::log1p(-1e-6));

    hipMemsetAsync(rowsum, 0, NN * sizeof(float), stream);  // hoisted: no bubble before zzt
    k_xw<<<NN / 4, dim3(64, 4), 0, stream>>>(x, Wg, Tt);
    k_adjT_mfma<<<dim3(64, KSPLIT), 256, 0, stream>>>(adj, Tt, partial);
    k_hred<<<NN * HH / 256, 256, 0, stream>>>(partial, bg, h);
    k_mlpZ<<<NN / 8, 256, 0, stream>>>(h, Wa1, ba1, Wa2, ba2, Zb);

    k_zzt_fused<<<528, 256, 0, stream>>>(Zb, out2, mask, rowsum,
                                         k1a, k1b, Lmin, Lmax);
    k_scale3<<<NN * NN / 4 / 256, 256, 0, stream>>>(mask, rowsum, out0);

    k_mlpM<<<NN / 8, 256, 0, stream>>>(h, Wx1, bx1, Wx2, bx2, x, out1,
                                       k2a, k2b, Lmin, Lmax);
}